// Round 1
// 64.937 us; speedup vs baseline: 1.0609x; 1.0609x over previous
//
#include <hip/hip_runtime.h>

// SetConv1dDecoder: out[b,m,c] = sum_n exp(-0.5*(x[b,m]-n/64)^2 * exp(-2*ls)) * z[b,c,n]
// scale = 1/32 => weight = exp(-0.125*(x*64-n)^2): underflows fp32 beyond |x*64-n|>26.5,
// so a 64-point window (lo = round(x*64)-32, 4-aligned) is exact to fp32 (R1/R2 verified).
//
// R4 layout (coalesced transpose of R3): one wave per (b,m);
//   lane = (col = lane&15 -> 4-float window chunk, row = lane>>4 -> channel group 4*row..4*row+3)
//  - Each of the 4 z loads is 4 contiguous 256B runs (lanes 0-15 = one channel's full
//    64-pt window). R3 had 64 distinct 64B lines PER load instr (16ch x 4chunk scatter)
//    -> TA/L1 address-divergence bound. Now 16 lines/instr, fully coalesced.
//  - Window weights computed ONCE per lane (4 exp instrs/wave vs 16 in R3) and reused
//    across all 4 channel-group loads.
//  - Reduction: 4 accumulators x 4-step shfl_xor butterfly within 16-lane groups
//    (16 shfl, DS-pipe, overlaps VALU).
//  - Store: lane col==0 of each row stores float4 {ch 4r..4r+3} -> 64B/wave coalesced.
//
// d_out layout (tuple return): [0,4096) = xz copy, [4096, 4096+B*M*C) = out.

#define N_GRID   4096
#define BATCH    4
#define M_TARGET 4096
#define C_CH     16

__global__ __launch_bounds__(256) void setconv_decoder_kernel(
    const float* __restrict__ xz,
    const float* __restrict__ x,
    const float* __restrict__ z,
    const float* __restrict__ log_scale,
    float* __restrict__ out)
{
    const int tid  = threadIdx.x;
    const int lane = tid & 63;
    const int wave = tid >> 6;
    const int bm   = blockIdx.x * 4 + wave;     // [0, B*M)
    const int b    = bm >> 12;                  // M_TARGET = 4096
    const int col  = lane & 15;                 // window chunk (4 floats each)
    const int row  = lane >> 4;                 // channel group base = 4*row

    // Tuple output element 0: copy xz (first 16 blocks cover 4096 floats).
    const int gt = blockIdx.x * 256 + tid;
    if (gt < N_GRID) out[gt] = xz[gt];

    const float xv   = x[bm];
    const float ls   = log_scale[0];
    const float coef = -0.5f * __expf(-2.0f * ls);   // = -512 here

    // 64-wide window, clamped, 4-aligned (still covers the +/-27 support).
    int lo = (int)(xv * 64.0f + 0.5f) - 32;
    lo = lo < 0 ? 0 : (lo > (N_GRID - 64) ? (N_GRID - 64) : lo);
    lo &= ~3;

    const int   n0    = lo + 4 * col;           // this lane's 4-point chunk
    const float inv64 = 0.015625f;

    // Weights for this lane's 4 points -- shared across all 4 channel groups.
    const float d0 = xv - (float)n0 * inv64;
    const float d1 = d0 - inv64;
    const float d2 = d0 - 2.0f * inv64;
    const float d3 = d0 - 3.0f * inv64;
    const float w0 = __expf(coef * d0 * d0);
    const float w1 = __expf(coef * d1 * d1);
    const float w2 = __expf(coef * d2 * d2);
    const float w3 = __expf(coef * d3 * d3);

    // Coalesced loads: channel stride = N_GRID floats = 1024 float4.
    const float4* __restrict__ zp =
        (const float4*)(z + ((size_t)(b * C_CH + 4 * row)) * N_GRID + n0);

    const float4 zv0 = zp[0];          // channel 4*row + 0
    const float4 zv1 = zp[1024];       // channel 4*row + 1
    const float4 zv2 = zp[2048];       // channel 4*row + 2
    const float4 zv3 = zp[3072];       // channel 4*row + 3

    float a0 = w0 * zv0.x + w1 * zv0.y + w2 * zv0.z + w3 * zv0.w;
    float a1 = w0 * zv1.x + w1 * zv1.y + w2 * zv1.z + w3 * zv1.w;
    float a2 = w0 * zv2.x + w1 * zv2.y + w2 * zv2.z + w3 * zv2.w;
    float a3 = w0 * zv3.x + w1 * zv3.y + w2 * zv3.z + w3 * zv3.w;

    // Butterfly-reduce each accumulator across the 16 lanes of its row group
    // (masks < 16 never cross the row boundary).
    #pragma unroll
    for (int m = 1; m <= 8; m <<= 1) {
        a0 += __shfl_xor(a0, m, 64);
        a1 += __shfl_xor(a1, m, 64);
        a2 += __shfl_xor(a2, m, 64);
        a3 += __shfl_xor(a3, m, 64);
    }

    // Lane col==0 of each row stores its 4 contiguous channels (16B aligned).
    if (col == 0) {
        *(float4*)(out + N_GRID + (size_t)bm * C_CH + 4 * row) =
            make_float4(a0, a1, a2, a3);
    }
}

extern "C" void kernel_launch(void* const* d_in, const int* in_sizes, int n_in,
                              void* d_out, int out_size, void* d_ws, size_t ws_size,
                              hipStream_t stream) {
    const float* xz = (const float*)d_in[0];   // [N_GRID, 1]
    const float* x  = (const float*)d_in[1];   // [B, M, 1]
    const float* z  = (const float*)d_in[2];   // [B, C, N_GRID]
    const float* ls = (const float*)d_in[3];   // scalar
    float* out = (float*)d_out;

    const int n_bm = BATCH * M_TARGET;                 // 16384 waves / 4 per block
    setconv_decoder_kernel<<<dim3(n_bm / 4), dim3(256), 0, stream>>>(
        xz, x, z, ls, out);
}

// Round 2
// 63.171 us; speedup vs baseline: 1.0905x; 1.0279x over previous
//
#include <hip/hip_runtime.h>

// SetConv1dDecoder: out[b,m,c] = sum_n exp(-0.5*(x[b,m]-n/64)^2 * exp(-2*ls)) * z[b,c,n]
// scale = 1/32 => weight = exp(-0.125*(x*64-n)^2).
//
// R5: 32-point window + 2 bm per wave.
//  - Window shrink: weight < 1e-8 for |x*64-n| >= 12.5. With round + 4-align the
//    32-pt window [lo, lo+31] guarantees coverage radius >= 11.5 on the worst side,
//    dropped-tail error <= ~4e-7 (absmax budget 1.6e-2). Halves loads/FMAs vs R4.
//  - Lane layout: bmh = lane>>5 (which of 2 bm), row = (lane>>3)&3 (channel group
//    4*row..4*row+3), col = lane&7 (4-float window chunk).
//  - Per load instr: 2bm x 4ch-groups = 8 contiguous 128B runs (~16 lines, coalesced,
//    same quality as R4's pattern).
//  - Weights computed once per lane (4 exp instrs/wave covering 2 bm = 2 exp/bm).
//  - Reduction: 3-step shfl_xor butterfly (masks 1,2,4) within 8-lane col groups,
//    never crossing row/bm boundaries. 12 shfl/wave = 6/bm (vs 16/bm in R4).
//  - Store: col==0 lanes (8/wave) each store float4 -> two 64B segments/wave.
//  - 8192 waves / 2048 blocks -> 8 blocks/CU, full 32-wave occupancy.
//
// d_out layout (tuple return): [0,4096) = xz copy, [4096, 4096+B*M*C) = out.

#define N_GRID   4096
#define BATCH    4
#define M_TARGET 4096
#define C_CH     16
#define WIN      32

__global__ __launch_bounds__(256) void setconv_decoder_kernel(
    const float* __restrict__ xz,
    const float* __restrict__ x,
    const float* __restrict__ z,
    const float* __restrict__ log_scale,
    float* __restrict__ out)
{
    const int tid  = threadIdx.x;
    const int lane = tid & 63;
    const int wave = tid >> 6;
    const int bmh  = lane >> 5;                 // which of the 2 bm rows
    const int col  = lane & 7;                  // 4-float window chunk (8 chunks = 32 pts)
    const int row  = (lane >> 3) & 3;           // channel group base = 4*row
    const int bm   = blockIdx.x * 8 + wave * 2 + bmh;   // [0, B*M)
    const int b    = bm >> 12;                  // M_TARGET = 4096

    // Tuple output element 0: copy xz (first 16 blocks cover 4096 floats).
    const int gt = blockIdx.x * 256 + tid;
    if (gt < N_GRID) out[gt] = xz[gt];

    const float xv   = x[bm];
    const float ls   = log_scale[0];
    const float coef = -0.5f * __expf(-2.0f * ls);   // = -512 here

    // 32-wide window, clamped, 4-aligned (covers the >=11.5-radius support).
    int lo = (int)(xv * 64.0f + 0.5f) - 16;
    lo = lo < 0 ? 0 : (lo > (N_GRID - WIN) ? (N_GRID - WIN) : lo);
    lo &= ~3;

    const int   n0    = lo + 4 * col;           // this lane's 4-point chunk
    const float inv64 = 0.015625f;

    // Weights for this lane's 4 points -- shared across its 4 channels.
    const float d0 = xv - (float)n0 * inv64;
    const float d1 = d0 - inv64;
    const float d2 = d0 - 2.0f * inv64;
    const float d3 = d0 - 3.0f * inv64;
    const float w0 = __expf(coef * d0 * d0);
    const float w1 = __expf(coef * d1 * d1);
    const float w2 = __expf(coef * d2 * d2);
    const float w3 = __expf(coef * d3 * d3);

    // Coalesced loads: channel stride = N_GRID floats = 1024 float4.
    const float4* __restrict__ zp =
        (const float4*)(z + ((size_t)(b * C_CH + 4 * row)) * N_GRID + n0);

    const float4 zv0 = zp[0];          // channel 4*row + 0
    const float4 zv1 = zp[1024];       // channel 4*row + 1
    const float4 zv2 = zp[2048];       // channel 4*row + 2
    const float4 zv3 = zp[3072];       // channel 4*row + 3

    float a0 = w0 * zv0.x + w1 * zv0.y + w2 * zv0.z + w3 * zv0.w;
    float a1 = w0 * zv1.x + w1 * zv1.y + w2 * zv1.z + w3 * zv1.w;
    float a2 = w0 * zv2.x + w1 * zv2.y + w2 * zv2.z + w3 * zv2.w;
    float a3 = w0 * zv3.x + w1 * zv3.y + w2 * zv3.z + w3 * zv3.w;

    // Butterfly-reduce each accumulator across the 8 col lanes of its group
    // (masks 1,2,4 never cross the row/bm boundary at bit 3).
    #pragma unroll
    for (int m = 1; m <= 4; m <<= 1) {
        a0 += __shfl_xor(a0, m, 64);
        a1 += __shfl_xor(a1, m, 64);
        a2 += __shfl_xor(a2, m, 64);
        a3 += __shfl_xor(a3, m, 64);
    }

    // Lane col==0 of each (bmh,row) group stores its 4 contiguous channels.
    if (col == 0) {
        *(float4*)(out + N_GRID + (size_t)bm * C_CH + 4 * row) =
            make_float4(a0, a1, a2, a3);
    }
}

extern "C" void kernel_launch(void* const* d_in, const int* in_sizes, int n_in,
                              void* d_out, int out_size, void* d_ws, size_t ws_size,
                              hipStream_t stream) {
    const float* xz = (const float*)d_in[0];   // [N_GRID, 1]
    const float* x  = (const float*)d_in[1];   // [B, M, 1]
    const float* z  = (const float*)d_in[2];   // [B, C, N_GRID]
    const float* ls = (const float*)d_in[3];   // scalar
    float* out = (float*)d_out;

    const int n_bm = BATCH * M_TARGET;         // 16384 bm rows, 8 per block
    setconv_decoder_kernel<<<dim3(n_bm / 8), dim3(256), 0, stream>>>(
        xz, x, z, ls, out);
}

// Round 3
// 63.098 us; speedup vs baseline: 1.0918x; 1.0012x over previous
//
#include <hip/hip_runtime.h>

// SetConv1dDecoder: out[b,m,c] = sum_n exp(-0.5*(x[b,m]-n/64)^2 * exp(-2*ls)) * z[b,c,n]
// scale = 1/32 => weight = exp(-0.125*(x*64-n)^2).
//
// R6: 4 bm per wave (R5 was 2).
//  - Window: 32-pt, 4-aligned (coverage radius >= 11.5, tail error <= ~4e-7; R5-verified).
//  - Lane layout: bmh = lane>>4 (which of 4 bm), row = (lane>>2)&3 (channel group
//    4*row..4*row+3), col = lane&3 (8-pt window chunk = 2 float4).
//  - Per lane: 8 weights (8 exp, shared across its 4 channels), 8 float4 loads
//    (2 consecutive per channel -> 2x MLP of R5, compensating halved wave count),
//    32 FMA, 4 accumulators.
//  - Reduction: 2-step shfl_xor butterfly (masks 1,2) within 4-lane col groups,
//    never crossing row (bit 2) or bm (bit 4) boundaries. 8 shfl/wave = 2/bm (R5: 6/bm).
//  - Setup (x load, window calc, coef, addresses) amortized over 4 bm.
//  - Store: col==0 lanes (16/wave) store float4; rows 0-3 of each bmh contiguous 64B.
//  - 4096 waves / 1024 blocks -> 4 blocks/CU, 4 waves/SIMD.
//
// d_out layout (tuple return): [0,4096) = xz copy, [4096, 4096+B*M*C) = out.

#define N_GRID   4096
#define BATCH    4
#define M_TARGET 4096
#define C_CH     16
#define WIN      32

__global__ __launch_bounds__(256) void setconv_decoder_kernel(
    const float* __restrict__ xz,
    const float* __restrict__ x,
    const float* __restrict__ z,
    const float* __restrict__ log_scale,
    float* __restrict__ out)
{
    const int tid  = threadIdx.x;
    const int lane = tid & 63;
    const int wave = tid >> 6;
    const int bmh  = lane >> 4;                 // which of the 4 bm rows
    const int row  = (lane >> 2) & 3;           // channel group base = 4*row
    const int col  = lane & 3;                  // 8-pt window chunk (4 chunks = 32 pts)
    const int bm   = blockIdx.x * 16 + wave * 4 + bmh;  // [0, B*M)
    const int b    = bm >> 12;                  // M_TARGET = 4096

    // Tuple output element 0: copy xz (first 16 blocks cover 4096 floats).
    const int gt = blockIdx.x * 256 + tid;
    if (gt < N_GRID) out[gt] = xz[gt];

    const float xv   = x[bm];
    const float ls   = log_scale[0];
    const float coef = -0.5f * __expf(-2.0f * ls);   // = -512 here

    // 32-wide window, clamped, 4-aligned (covers the >=11.5-radius support).
    int lo = (int)(xv * 64.0f + 0.5f) - 16;
    lo = lo < 0 ? 0 : (lo > (N_GRID - WIN) ? (N_GRID - WIN) : lo);
    lo &= ~3;

    const int   n0    = lo + 8 * col;           // this lane's 8-point chunk
    const float inv64 = 0.015625f;

    // Weights for this lane's 8 points -- shared across its 4 channels.
    const float d0 = xv - (float)n0 * inv64;
    const float d1 = d0 - inv64;
    const float d2 = d0 - 2.0f * inv64;
    const float d3 = d0 - 3.0f * inv64;
    const float d4 = d0 - 4.0f * inv64;
    const float d5 = d0 - 5.0f * inv64;
    const float d6 = d0 - 6.0f * inv64;
    const float d7 = d0 - 7.0f * inv64;
    const float w0 = __expf(coef * d0 * d0);
    const float w1 = __expf(coef * d1 * d1);
    const float w2 = __expf(coef * d2 * d2);
    const float w3 = __expf(coef * d3 * d3);
    const float w4 = __expf(coef * d4 * d4);
    const float w5 = __expf(coef * d5 * d5);
    const float w6 = __expf(coef * d6 * d6);
    const float w7 = __expf(coef * d7 * d7);

    // Coalesced loads: channel stride = N_GRID floats = 1024 float4.
    const float4* __restrict__ zp =
        (const float4*)(z + ((size_t)(b * C_CH + 4 * row)) * N_GRID + n0);

    const float4 za0 = zp[0],    zb0 = zp[1];       // channel 4*row + 0
    const float4 za1 = zp[1024], zb1 = zp[1025];    // channel 4*row + 1
    const float4 za2 = zp[2048], zb2 = zp[2049];    // channel 4*row + 2
    const float4 za3 = zp[3072], zb3 = zp[3073];    // channel 4*row + 3

    float a0 = w0*za0.x + w1*za0.y + w2*za0.z + w3*za0.w
             + w4*zb0.x + w5*zb0.y + w6*zb0.z + w7*zb0.w;
    float a1 = w0*za1.x + w1*za1.y + w2*za1.z + w3*za1.w
             + w4*zb1.x + w5*zb1.y + w6*zb1.z + w7*zb1.w;
    float a2 = w0*za2.x + w1*za2.y + w2*za2.z + w3*za2.w
             + w4*zb2.x + w5*zb2.y + w6*zb2.z + w7*zb2.w;
    float a3 = w0*za3.x + w1*za3.y + w2*za3.z + w3*za3.w
             + w4*zb3.x + w5*zb3.y + w6*zb3.z + w7*zb3.w;

    // Butterfly-reduce each accumulator across the 4 col lanes of its group
    // (masks 1,2 never cross the row boundary at bit 2).
    #pragma unroll
    for (int m = 1; m <= 2; m <<= 1) {
        a0 += __shfl_xor(a0, m, 64);
        a1 += __shfl_xor(a1, m, 64);
        a2 += __shfl_xor(a2, m, 64);
        a3 += __shfl_xor(a3, m, 64);
    }

    // Lane col==0 of each (bmh,row) group stores its 4 contiguous channels.
    if (col == 0) {
        *(float4*)(out + N_GRID + (size_t)bm * C_CH + 4 * row) =
            make_float4(a0, a1, a2, a3);
    }
}

extern "C" void kernel_launch(void* const* d_in, const int* in_sizes, int n_in,
                              void* d_out, int out_size, void* d_ws, size_t ws_size,
                              hipStream_t stream) {
    const float* xz = (const float*)d_in[0];   // [N_GRID, 1]
    const float* x  = (const float*)d_in[1];   // [B, M, 1]
    const float* z  = (const float*)d_in[2];   // [B, C, N_GRID]
    const float* ls = (const float*)d_in[3];   // scalar
    float* out = (float*)d_out;

    const int n_bm = BATCH * M_TARGET;         // 16384 bm rows, 16 per block
    setconv_decoder_kernel<<<dim3(n_bm / 16), dim3(256), 0, stream>>>(
        xz, x, z, ls, out);
}